// Round 6
// baseline (52.444 us; speedup 1.0000x reference)
//
#include <hip/hip_runtime.h>
#include <cstddef>

#define POOL 7
#define NEGV (-3e38f)
#define NPOOLS 32
#define TPP 1792          // tasks per pool: 57344 / 32
#define CTRSTRIDE 16      // uints per counter slot (64 B padding)

__device__ __forceinline__ float4 fmax4(float4 a, float4 b) {
    return make_float4(fmaxf(a.x, b.x), fmaxf(a.y, b.y),
                       fmaxf(a.z, b.z), fmaxf(a.w, b.w));
}

// Load & max-reduce exactly N rows of the lane's quad column. Loads batched
// (<=5 in flight) before any fmax; addresses exact (no clamping needed).
template<int N>
__device__ __forceinline__ float4 colmax_n(const float4* __restrict__ fp4,
                                           int ys, int xq) {
    constexpr int B1 = (N <= 6) ? N : (N + 1) / 2;
    float4 m = make_float4(NEGV, NEGV, NEGV, NEGV);
#pragma unroll
    for (int bb = 0; bb < N; bb += B1) {
        float4 t[B1];
#pragma unroll
        for (int k = 0; k < B1; ++k)
            if (bb + k < N) t[k] = fp4[((ys + bb + k) << 4) + xq];
#pragma unroll
        for (int k = 0; k < B1; ++k)
            if (bb + k < N) m = fmax4(m, t[k]);
    }
    return m;
}

// Exact-width LDS row reduce; clamped duplicate reads are max-idempotent.
template<int KW>
__device__ __forceinline__ float rowmax_lds(const float* __restrict__ rrow,
                                            int xs, int xec) {
    float t[KW];
#pragma unroll
    for (int k = 0; k < KW; ++k) t[k] = rrow[min(xs + k, xec)];
    float m = t[0];
#pragma unroll
    for (int k = 1; k < KW; ++k) m = fmaxf(m, t[k]);
    return m;
}

// Persistent waves + 32-pool atomic work queue. Task = one pooled row (i) of
// one 4-channel group (c4) of one ROI (br). Pool k covers c4 in {2k,2k+1} for
// ALL 128 ROIs -> pool work sums are equal; within-pool balance via queue.
__global__ __launch_bounds__(256) void roi_pool_kernel(
    const float* __restrict__ feat, const float4* __restrict__ rois4,
    float* __restrict__ out, unsigned int* __restrict__ ctrs)
{
    const int tid  = threadIdx.x;
    const int lane = tid & 63;
    const int wv   = tid >> 6;
    const int pool = blockIdx.x & (NPOOLS - 1);
    unsigned int* ctr = ctrs + pool * CTRSTRIDE;

    const int cs = lane >> 4;       // channel slot 0..3
    const int lx = lane & 15;       // quad slot 0..15
    const int li = min(lane, 27);   // clamped phase-2 lane (keeps LDS reads in range)
    const int i7 = li / 7;          // channel slot for phase 2
    const int j7 = li - i7 * 7;     // pooled column
    const bool active = lane < 28;

    __shared__ __attribute__((aligned(16))) float lds[4][4][64];
    float* ldsw = &lds[wv][0][0];

    // ---- grab first ticket + prefetch its ROI ----
    unsigned int nt = 0;
    if (lane == 0) nt = atomicAdd(ctr, 1u);
    nt = __builtin_amdgcn_readfirstlane(nt);
    float4 rv;
    {
        const unsigned tq = min(nt, (unsigned)(TPP - 1)) / 7u;
        rv = rois4[tq & 127u];
    }

    while (nt < TPP) {
        const unsigned cur = nt;
        const float4 rcur = rv;
        // pipeline: grab next ticket + prefetch next ROI under current work
        if (lane == 0) nt = atomicAdd(ctr, 1u);
        nt = __builtin_amdgcn_readfirstlane(nt);
        {
            const unsigned tq = min(nt, (unsigned)(TPP - 1)) / 7u;
            rv = rois4[tq & 127u];
        }

        // ---- task decode ----
        const unsigned tq = cur / 7u;
        const int i  = (int)(cur - tq * 7u);            // pooled row
        const int br = (int)(tq & 127u);                // b*64 + r
        const int c4 = (pool << 1) + (int)(tq >> 7);    // channel quad-group
        const int b  = br >> 6;

        const int px = __builtin_amdgcn_readfirstlane(__float2int_rn(rcur.x * 0.0625f));
        const int py = __builtin_amdgcn_readfirstlane(__float2int_rn(rcur.y * 0.0625f));
        const int qx = __builtin_amdgcn_readfirstlane(__float2int_rn(rcur.z * 0.0625f));
        const int qy = __builtin_amdgcn_readfirstlane(__float2int_rn(rcur.w * 0.0625f));
        const int roi_w = max(qx - px + 1, 1);
        const int roi_h = max(qy - py + 1, 1);
        const int psw = (roi_w + POOL - 1) / POOL;
        const int psh = (roi_h + POOL - 1) / POOL;
        const int pad_l = (psw * POOL - roi_w) >> 1;
        const int pad_t = (psh * POOL - roi_h) >> 1;

        // exact y-window of pooled row i
        const int lo = max(i * psh - pad_t, 0);
        const int hi = min((i + 1) * psh - pad_t, roi_h) - 1;
        const int wlen = hi - lo + 1;                   // <=0 if empty
        const int ys = py + lo;

        // lane's quad column (clamped dup lanes load identical data)
        const int qbase = px >> 2;
        const int nq = (qx >> 2) - qbase + 1;
        const int xq = qbase + min(lx, nq - 1);

        const int c = (c4 << 2) + cs;
        const float4* fp4 = (const float4*)feat + ((size_t)((b << 8) + c) << 10);

        // ---- phase 1: column maxes, exact ladder on window height ----
        float4 m4 = make_float4(NEGV, NEGV, NEGV, NEGV);
        switch (wlen) {
            case 1:  m4 = colmax_n<1 >(fp4, ys, xq); break;
            case 2:  m4 = colmax_n<2 >(fp4, ys, xq); break;
            case 3:  m4 = colmax_n<3 >(fp4, ys, xq); break;
            case 4:  m4 = colmax_n<4 >(fp4, ys, xq); break;
            case 5:  m4 = colmax_n<5 >(fp4, ys, xq); break;
            case 6:  m4 = colmax_n<6 >(fp4, ys, xq); break;
            case 7:  m4 = colmax_n<7 >(fp4, ys, xq); break;
            case 8:  m4 = colmax_n<8 >(fp4, ys, xq); break;
            case 9:  m4 = colmax_n<9 >(fp4, ys, xq); break;
            case 10: m4 = colmax_n<10>(fp4, ys, xq); break;
            default: break;                            // empty window
        }

        // ---- LDS handoff (same wave, in-order DS pipe: no barrier) ----
        *(float4*)(ldsw + (cs << 6) + ((xq - qbase) << 2)) = m4;

        // ---- phase 2: reduce along x, pad rule, store ----
        const int pxl = px & 3;
        const int lox = max(j7 * psw - pad_l, 0);
        const int hix = min((j7 + 1) * psw - pad_l, roi_w) - 1;
        const int xs  = pxl + lox;
        const int xe  = pxl + hix;
        const int xec = max(xe, 0);
        const float* rrow = ldsw + (i7 << 6);
        float m;
        switch (psw) {
            case 1:  m = rowmax_lds<1 >(rrow, xs, xec); break;
            case 2:  m = rowmax_lds<2 >(rrow, xs, xec); break;
            case 3:  m = rowmax_lds<3 >(rrow, xs, xec); break;
            case 4:  m = rowmax_lds<4 >(rrow, xs, xec); break;
            case 5:  m = rowmax_lds<5 >(rrow, xs, xec); break;
            case 6:  m = rowmax_lds<6 >(rrow, xs, xec); break;
            case 7:  m = rowmax_lds<7 >(rrow, xs, xec); break;
            case 8:  m = rowmax_lds<8 >(rrow, xs, xec); break;
            case 9:  m = rowmax_lds<9 >(rrow, xs, xec); break;
            default: m = rowmax_lds<10>(rrow, xs, xec); break;
        }
        if ((xe < xs) | (wlen <= 0)) m = NEGV;
        const bool padr = (i * psh < pad_t) | ((i + 1) * psh > pad_t + roi_h);
        const bool padc = (j7 * psw < pad_l) | ((j7 + 1) * psw > pad_l + roi_w);
        if (padr | padc) m = fmaxf(m, 0.0f);
        if (active)
            out[((size_t)(br << 8) + (c4 << 2) + i7) * 49 + i * 7 + j7] = m;
    }
}

extern "C" void kernel_launch(void* const* d_in, const int* in_sizes, int n_in,
                              void* d_out, int out_size, void* d_ws, size_t ws_size,
                              hipStream_t stream) {
    const float* feat = (const float*)d_in[0];
    const float* rois = (const float*)d_in[1];
    float* out = (float*)d_out;

    // reset the 32 queue counters (64 B apart) each launch
    hipMemsetAsync(d_ws, 0, NPOOLS * CTRSTRIDE * sizeof(unsigned int), stream);

    // persistent grid: 2048 blocks = 8 blocks/CU fully resident; queue drains
    roi_pool_kernel<<<2048, 256, 0, stream>>>(
        feat, (const float4*)rois, out, (unsigned int*)d_ws);
}

// Round 7
// 17.193 us; speedup vs baseline: 3.0503x; 3.0503x over previous
//
#include <hip/hip_runtime.h>
#include <cstddef>

#define POOL 7
#define NEGV (-3e38f)

__device__ __forceinline__ float4 fmax4(float4 a, float4 b) {
    return make_float4(fmaxf(a.x, b.x), fmaxf(a.y, b.y),
                       fmaxf(a.z, b.z), fmaxf(a.w, b.w));
}

// Phase 1: per-lane column maxes (1 quad = 4 columns) for the 7 pooled rows.
// Loads batched into statically-indexed register arrays before any fmax ->
// back-to-back global_load_dwordx4, one vmcnt wait per batch. y addresses are
// SGPR-uniform; clamped re-loads of the last valid row are max-idempotent.
template<int KL>
__device__ __forceinline__ void col_max4(const float4* __restrict__ fp4,
        int py, int psh, int pad_t, int roi_h, int xq, float4 (&acc)[POOL]) {
    constexpr int B1 = (KL <= 6) ? KL : (KL + 1) / 2;   // batch size (10->5, 8->4)
    constexpr int NB = (KL + B1 - 1) / B1;
#pragma unroll
    for (int i = 0; i < POOL; ++i) {
        const int lo = max(i * psh - pad_t, 0);
        const int hi = min((i + 1) * psh - pad_t, roi_h) - 1;
        const int ys = py + lo;
        const int yc = min(py + max(hi, lo), 63);       // empty-safe, in-bounds
        float4 m = make_float4(NEGV, NEGV, NEGV, NEGV);
#pragma unroll
        for (int bb = 0; bb < NB; ++bb) {
            float4 t[B1];
#pragma unroll
            for (int k = 0; k < B1; ++k) {
                const int y = min(ys + bb * B1 + k, yc);   // scalar chain
                t[k] = fp4[(y << 4) + xq];
            }
#pragma unroll
            for (int k = 0; k < B1; ++k) m = fmax4(m, t[k]);
        }
        if (lo > hi) m = make_float4(NEGV, NEGV, NEGV, NEGV);
        acc[i] = m;
    }
}

// Phase 2: parity-double-buffered LDS handoff (wave-in-order DS pipe, no
// barriers). Reads batched into registers -> one lgkm wait per pooled row.
template<int KW>
__device__ __forceinline__ void phase2_run(const float4 (&acc)[POOL],
        float* ldsbase, int Lq, int cs, bool active, int i7,
        int xs, int xec, bool xempty, bool padc,
        int psh, int pad_t, int roi_h,
        float* __restrict__ out, size_t obase) {
#pragma unroll
    for (int i = 0; i < POOL; ++i) {
        float* wrow = ldsbase + (((i & 1) << 2) + cs) * 64;
        *(float4*)(wrow + (Lq << 2)) = acc[i];
        if (active) {
            const float* rrow = ldsbase + (((i & 1) << 2) + i7) * 64;
            float t[KW];
#pragma unroll
            for (int k = 0; k < KW; ++k) t[k] = rrow[min(xs + k, xec)];
            float m = t[0];
#pragma unroll
            for (int k = 1; k < KW; ++k) m = fmaxf(m, t[k]);
            if (xempty) m = NEGV;
            const bool padr = (i * psh < pad_t) | ((i + 1) * psh > pad_t + roi_h);
            if (padr | padc) m = fmaxf(m, 0.0f);
            out[obase + (size_t)i * 7] = m;
        }
    }
}

__global__ __launch_bounds__(256) void roi_pool_kernel(
    const float* __restrict__ feat, const float* __restrict__ rois,
    float* __restrict__ out)
{
    const int tid  = threadIdx.x;
    const int lane = tid & 63;
    const int wv   = tid >> 6;
    const int bid  = blockIdx.x;

    // XCD-aware decode: blocks with bid%8 == x (round-robin onto XCD x) own a
    // fixed 32-channel slice -> per-XCD feature working set = 1 MB (L2-fits).
    // Bijective: bid = (br<<4) | (cglo<<3) | (cg>>1), cg = ((bid&7)<<1)|cglo.
    const int br = bid >> 4;                                // b*64 + r
    const int cg = ((bid & 7) << 1) | ((bid >> 3) & 1);     // channel group 0..15
    const int b  = br >> 6;
    const int c0 = (cg << 4) + (wv << 2);                   // wave's first channel
    const int cs = lane >> 4;                               // channel slot 0..3
    const int lx = lane & 15;                               // quad slot 0..15

    // ---- ROI decode; force SGPR so downstream address math scalarizes ----
    const float* rp = rois + (size_t)br * 4;
    const int px = __builtin_amdgcn_readfirstlane(__float2int_rn(rp[0] * 0.0625f));
    const int py = __builtin_amdgcn_readfirstlane(__float2int_rn(rp[1] * 0.0625f));
    const int qx = __builtin_amdgcn_readfirstlane(__float2int_rn(rp[2] * 0.0625f));
    const int qy = __builtin_amdgcn_readfirstlane(__float2int_rn(rp[3] * 0.0625f));
    const int roi_w = max(qx - px + 1, 1);
    const int roi_h = max(qy - py + 1, 1);
    const int psw = (roi_w + POOL - 1) / POOL;
    const int psh = (roi_h + POOL - 1) / POOL;
    const int pad_l = (psw * POOL - roi_w) >> 1;
    const int pad_t = (psh * POOL - roi_h) >> 1;

    // quad coverage of [px,qx]; clamped duplicate lanes hit the same lines
    const int qbase = px >> 2;
    const int nq    = (qx >> 2) - qbase + 1;
    const int Lq    = min(lx, nq - 1);
    const int xq    = qbase + Lq;

    const int c = c0 + cs;
    const float4* fp4 = (const float4*)feat + ((size_t)((b << 8) + c) << 10);

    // ---- phase 1 (exact tier ladder on psh; big tiers split into 2 batches) ----
    float4 acc[POOL];
    switch (psh) {
        case 1:  col_max4<1 >(fp4, py, psh, pad_t, roi_h, xq, acc); break;
        case 2:  col_max4<2 >(fp4, py, psh, pad_t, roi_h, xq, acc); break;
        case 3:  col_max4<3 >(fp4, py, psh, pad_t, roi_h, xq, acc); break;
        case 4:  col_max4<4 >(fp4, py, psh, pad_t, roi_h, xq, acc); break;
        case 5:  col_max4<5 >(fp4, py, psh, pad_t, roi_h, xq, acc); break;
        case 6:  col_max4<6 >(fp4, py, psh, pad_t, roi_h, xq, acc); break;
        case 7:
        case 8:  col_max4<8 >(fp4, py, psh, pad_t, roi_h, xq, acc); break;
        default: col_max4<10>(fp4, py, psh, pad_t, roi_h, xq, acc); break;
    }

    // ---- phase 2 setup (active lanes: i7 = channel slot, j7 = pooled col) ----
    __shared__ __attribute__((aligned(16))) float lds[4][2][4][64];
    const bool active = lane < 28;
    const int i7  = lane / 7;
    const int j7  = lane - i7 * 7;
    const int pxl = px & 3;
    const int lox = max(j7 * psw - pad_l, 0);
    const int hix = min((j7 + 1) * psw - pad_l, roi_w) - 1;
    const int xs  = pxl + lox;                 // >= 0
    const int xe  = pxl + hix;                 // <= 63; < xs if empty
    const int xec = max(xe, 0);
    const bool xempty = xe < xs;
    const bool padc = (j7 * psw < pad_l) | ((j7 + 1) * psw > pad_l + roi_w);
    const size_t obase = ((size_t)(br << 8) + c0 + i7) * 49 + j7;
    float* ldsbase = &lds[wv][0][0][0];

    switch (psw) {
        case 1:  phase2_run<1 >(acc, ldsbase, Lq, cs, active, i7, xs, xec, xempty, padc, psh, pad_t, roi_h, out, obase); break;
        case 2:  phase2_run<2 >(acc, ldsbase, Lq, cs, active, i7, xs, xec, xempty, padc, psh, pad_t, roi_h, out, obase); break;
        case 3:  phase2_run<3 >(acc, ldsbase, Lq, cs, active, i7, xs, xec, xempty, padc, psh, pad_t, roi_h, out, obase); break;
        case 4:  phase2_run<4 >(acc, ldsbase, Lq, cs, active, i7, xs, xec, xempty, padc, psh, pad_t, roi_h, out, obase); break;
        case 5:  phase2_run<5 >(acc, ldsbase, Lq, cs, active, i7, xs, xec, xempty, padc, psh, pad_t, roi_h, out, obase); break;
        case 6:  phase2_run<6 >(acc, ldsbase, Lq, cs, active, i7, xs, xec, xempty, padc, psh, pad_t, roi_h, out, obase); break;
        case 7:
        case 8:  phase2_run<8 >(acc, ldsbase, Lq, cs, active, i7, xs, xec, xempty, padc, psh, pad_t, roi_h, out, obase); break;
        default: phase2_run<10>(acc, ldsbase, Lq, cs, active, i7, xs, xec, xempty, padc, psh, pad_t, roi_h, out, obase); break;
    }
}

extern "C" void kernel_launch(void* const* d_in, const int* in_sizes, int n_in,
                              void* d_out, int out_size, void* d_ws, size_t ws_size,
                              hipStream_t stream) {
    const float* feat = (const float*)d_in[0];
    const float* rois = (const float*)d_in[1];
    float* out = (float*)d_out;

    // 2*64 ROIs x 256 channels; 4 channels/wave, 4 waves/block -> 2048 blocks
    const int blocks = 2 * 64 * 256 / 16;
    roi_pool_kernel<<<blocks, 256, 0, stream>>>(feat, rois, out);
}